// Round 1
// baseline (142.643 us; speedup 1.0000x reference)
//
#include <hip/hip_runtime.h>

#define B_ 512
#define L_ 8192
#define N_ 128
#define S_ 256
#define DELIM_ 5
#define T_ 1024          // 16 waves/block
#define NW_ (T_ / 64)

// One block per row.
// Phase 1: coalesced int4 row read -> registers AND swizzled LDS (ds_write_b128
//          with in-register component permute); packed block scan -> ordered
//          delimiter positions -> chunk table.
// Phase 2: one sentence per wave per iteration; element layout e = 4*lane + j
//          so otp/mask go out as float4 (global_store_dwordx4, 4x fewer store
//          instructions than the dword version). LDS gather at stride 4 is
//          made conflict-free (2-way, free) by the XOR swizzle below.
//          ballot+popc for len_sent. No atomics.
//
// Swizzle: token at logical position p lives at LDS word  p ^ ((p>>5)&3).
//  - XOR value < 4 and p-groups are 4-aligned => permutation stays inside each
//    aligned 4-word group => phase-1 int4 writes stay b128 (components permuted).
//  - Phase-2 read p = start + 4*lane + j (j fixed): lanes l and l+32 alias a
//    bank, all others distinct => 2-way conflict = free (m136).
__device__ __forceinline__ int sw_idx(int p) { return p ^ ((p >> 5) & 3); }

__global__ __launch_bounds__(T_, 8) void split_kernel(const int* __restrict__ x,
                                                      float* __restrict__ otp,
                                                      float* __restrict__ len_doc,
                                                      float* __restrict__ mask) {
    const int b = blockIdx.x;
    const int t = threadIdx.x;
    const int lane = t & 63;
    const int w = t >> 6;
    const int* __restrict__ row = x + (size_t)b * L_;

    __shared__ __align__(16) int s_row[L_ + 1];  // swizzled row + trailing DELIM
    __shared__ int s_wsum[NW_];
    __shared__ int s_dpos[N_ - 1];  // first 127 delimiter positions (tail merge)
    __shared__ int s_start[N_];
    __shared__ int s_cl[N_];        // copy length: 0 for empty/unused, else min(size, S)
    __shared__ int s_doc[NW_];

    // ---- phase 1a: coalesced int4 loads; stage into swizzled LDS; count delims ----
    const int4 r0 = ((const int4*)row)[t];        // tokens [4t, 4t+4)
    const int4 r1 = ((const int4*)row)[t + T_];   // tokens [4096+4t, ...)

    // word 4t+j must hold token 4t+(j^v)  =>  w[j] = r[j^v]
    const int v = (t >> 3) & 3;                   // same for t and t+T_ (T_/8 % 4 == 0)
    int4 w0 = r0, w1 = r1;
    if (v == 1)      { w0 = make_int4(r0.y, r0.x, r0.w, r0.z); w1 = make_int4(r1.y, r1.x, r1.w, r1.z); }
    else if (v == 2) { w0 = make_int4(r0.z, r0.w, r0.x, r0.y); w1 = make_int4(r1.z, r1.w, r1.x, r1.y); }
    else if (v == 3) { w0 = make_int4(r0.w, r0.z, r0.y, r0.x); w1 = make_int4(r1.w, r1.z, r1.y, r1.x); }
    ((int4*)s_row)[t] = w0;                       // ds_write_b128, conflict-free
    ((int4*)s_row)[t + T_] = w1;
    if (t == 0) s_row[L_] = DELIM_;               // rpad[L]; sw_idx(L_) == L_

    const int c0 = (r0.x == DELIM_) + (r0.y == DELIM_) + (r0.z == DELIM_) + (r0.w == DELIM_);
    const int c1 = (r1.x == DELIM_) + (r1.y == DELIM_) + (r1.z == DELIM_) + (r1.w == DELIM_);
    const int packed = c0 | (c1 << 16);

    // wave inclusive scan of packed counts
    int sv = packed;
#pragma unroll
    for (int d = 1; d < 64; d <<= 1) {
        int n = __shfl_up(sv, d, 64);
        if (lane >= d) sv += n;
    }
    if (lane == 63) s_wsum[w] = sv;
    __syncthreads();

    int woff = 0, tot = 0;
#pragma unroll
    for (int i = 0; i < NW_; ++i) {
        const int s = s_wsum[i];
        if (i < w) woff += s;
        tot += s;
    }
    const int pre = woff + sv - packed;         // exclusive prefix (packed)
    const int c0tot = tot & 0xffff;             // total delims in first half
    const int m = c0tot + (tot >> 16);          // total delims in row
    const int off0 = pre & 0xffff;
    const int off1 = c0tot + (pre >> 16);

    // ---- phase 1b: emit ordered delimiter positions from registers ----
    if (c0 > 0 && off0 < N_ - 1) {
        int o = off0;
        const int p = 4 * t;
        if (r0.x == DELIM_) { if (o < N_ - 1) s_dpos[o] = p;     ++o; }
        if (r0.y == DELIM_) { if (o < N_ - 1) s_dpos[o] = p + 1; ++o; }
        if (r0.z == DELIM_) { if (o < N_ - 1) s_dpos[o] = p + 2; ++o; }
        if (r0.w == DELIM_) { if (o < N_ - 1) s_dpos[o] = p + 3; ++o; }
    }
    if (c1 > 0 && off1 < N_ - 1) {
        int o = off1;
        const int p = 4 * T_ + 4 * t;
        if (r1.x == DELIM_) { if (o < N_ - 1) s_dpos[o] = p;     ++o; }
        if (r1.y == DELIM_) { if (o < N_ - 1) s_dpos[o] = p + 1; ++o; }
        if (r1.z == DELIM_) { if (o < N_ - 1) s_dpos[o] = p + 2; ++o; }
        if (r1.w == DELIM_) { if (o < N_ - 1) s_dpos[o] = p + 3; ++o; }
    }
    __syncthreads();

    // ---- phase 1c: chunk table ----
    if (t < N_) {
        const int k = t;
        const int mc = (m < N_ - 1) ? m : (N_ - 1);  // last used chunk index
        int start = 0, cl = 0;
        if (k <= mc) {
            start = (k == 0) ? 0 : (s_dpos[k - 1] + 1);
            const int end = (k < mc) ? s_dpos[k] : L_;  // rpad[L] = trailing DELIM
            const int size = end - start + 1;           // delimiter belongs to its chunk
            cl = (size <= 1) ? 0 : (size < S_ ? size : S_);  // lone delim -> all PAD
        }
        s_start[k] = start;
        s_cl[k] = cl;
    }
    __syncthreads();

    // ---- phase 2: wave w handles sentence k = i*NW_ + w (8 iterations) ----
    float* __restrict__ otp_b = otp + (size_t)b * N_ * S_;
    float* __restrict__ msk_b = mask + (size_t)b * N_ * S_;
    int doccnt = 0;
    const int e0 = lane << 2;                     // this lane's 4 contiguous elements
#pragma unroll
    for (int i = 0; i < (N_ / NW_); ++i) {
        const int k = i * NW_ + w;
        const int start = s_start[k];  // wave-uniform LDS broadcast
        const int cl = s_cl[k];
        float4 tf = make_float4(0.f, 0.f, 0.f, 0.f);
        float4 mk = make_float4(0.f, 0.f, 0.f, 0.f);
        int len = 0;
        if (cl > 0) {                  // wave-uniform: skip empty/unused chunks
            int t0 = 0, t1 = 0, t2 = 0, t3 = 0;
            if (e0 + 0 < cl) t0 = s_row[sw_idx(start + e0 + 0)];
            if (e0 + 1 < cl) t1 = s_row[sw_idx(start + e0 + 1)];
            if (e0 + 2 < cl) t2 = s_row[sw_idx(start + e0 + 2)];
            if (e0 + 3 < cl) t3 = s_row[sw_idx(start + e0 + 3)];
            len += __popcll(__ballot(t0 != 0));   // wave-uniform nonzero count
            len += __popcll(__ballot(t1 != 0));
            len += __popcll(__ballot(t2 != 0));
            len += __popcll(__ballot(t3 != 0));
            tf = make_float4((float)t0, (float)t1, (float)t2, (float)t3);
            mk = make_float4(e0 + 0 < len ? 1.f : 0.f, e0 + 1 < len ? 1.f : 0.f,
                             e0 + 2 < len ? 1.f : 0.f, e0 + 3 < len ? 1.f : 0.f);
        }
        ((float4*)(otp_b + (size_t)k * S_))[lane] = tf;   // global_store_dwordx4
        ((float4*)(msk_b + (size_t)k * S_))[lane] = mk;
        doccnt += (len > 0);
    }

    // ---- len_doc: one LDS reduction per block, no atomics ----
    if (lane == 0) s_doc[w] = doccnt;
    __syncthreads();
    if (t == 0) {
        int d = 0;
#pragma unroll
        for (int i = 0; i < NW_; ++i) d += s_doc[i];
        len_doc[b] = (float)d;
    }
}

extern "C" void kernel_launch(void* const* d_in, const int* in_sizes, int n_in,
                              void* d_out, int out_size, void* d_ws, size_t ws_size,
                              hipStream_t stream) {
    const int* x = (const int*)d_in[0];
    float* out = (float*)d_out;

    // d_out layout (flat, return order): otp[B*N*S] | len_doc[B] | mask[B*N*S]
    float* otp = out;
    float* len_doc = out + (size_t)B_ * N_ * S_;
    float* mask = len_doc + B_;

    split_kernel<<<B_, T_, 0, stream>>>(x, otp, len_doc, mask);
}